// Round 9
// baseline (111.230 us; speedup 1.0000x reference)
//
#include <hip/hip_runtime.h>
#include <math.h>

// ---------------------------------------------------------------------------
// PhysicsResonatorBank: B=8 notes, K=80 partials, NB=16 noise bands,
// N = n_frames*256 samples. out[b][c][n], c in {L,R}.
//
// Round-9: IDENTICAL to round 8 except __launch_bounds__ min-waves 8 -> 4,
// lifting the VGPR cap from 64 to 128. Hypothesis: at 64 VGPRs the
// register allocator cannot keep the 8 independent per-note sin chains
// in flight (serialization / spills), wasting ~half the issue slots.
// 4 waves/SIMD with 8-chain ILP should still hide latency (cf. rounds
// 3/4: ~75% VALUBusy at 4 waves/SIMD).
// Structure: 512 thr = 8 waves; wave g owns k-chunk g (10 partials) for
// 64 samples x all 8 notes; tables read via scalar loads (readfirstlane
// SGPR indices); full k-loop unroll (K=80 specialization); LDS only for
// the padded cross-wave reduction buffer [8][64][17].
// Arithmetic bit-identical to rounds 7/8: exp2f decay (pre-scaled by
// log2e), beat freq in revolutions (v_cos direct), sin via 2-term f32
// Cody-Waite reduction of the reference's exact f32 phase + __sinf.
// ---------------------------------------------------------------------------

#define NBMAX 32
#define NCH 8

#define C2PI_HI 6.28318548202514648f     // fl32(2*pi)
#define C2PI_LO -1.7484556e-7f           // fl32(2*pi - C2PI_HI)
#define INV2PI  0.15915494309189535f
#define LOG2E   1.44269504088896340736f

__device__ __forceinline__ float nofuse(float x) {
    asm volatile("" : "+v"(x));
    return x;
}

__device__ __forceinline__ float sin_cw(float ph) {
    float q = rintf(ph * INV2PI);
    float r = fmaf(q, -C2PI_HI, ph);
    r = fmaf(q, -C2PI_LO, r);
    return __sinf(r);
}

// ws layout (floats):
//  float4 pk4T[K*B] : [k][b] = {2pi*f, ampL, ampR, 0}
//  float4 ke8[2*K]  : [2k]   = {log2e/tau1, log2e/tau2, a1, 1-a1}
//                     [2k+1] = {beat_hz (rev/s), 0.5*depth, 0, 0}
//  float4 nz [NB]   : {2pi*nf, band_gain, 0, 0}
//  float  nl [B]    : exp(log_noise_level)*vel ; nl[B] = 1/tau_noise

__global__ void pr_precomp(const float* __restrict__ f0,
                           const float* __restrict__ vel,
                           const float* __restrict__ pslope,
                           const float* __restrict__ pinter,
                           const float* __restrict__ log_tau1,
                           const float* __restrict__ log_tau2,
                           const float* __restrict__ logit_a1,
                           const float* __restrict__ log_beat_hz,
                           const float* __restrict__ logit_beat_depth,
                           const float* __restrict__ log_A0,
                           const float* __restrict__ harm_detune,
                           const float* __restrict__ noise_band_gain,
                           const float* __restrict__ plog_tau_noise,
                           const float* __restrict__ plog_noise_level,
                           const float* __restrict__ ppan_scale,
                           float* __restrict__ ws, int B, int K, int NB) {
    const int tid = threadIdx.x;
    const int b = blockIdx.x;           // grid = B blocks
    const float two_pi = C2PI_HI;
    const float slope = pslope[0], inter = pinter[0], pan_scale = ppan_scale[0];

    float4* pk4T = (float4*)ws;
    float4* ke8 = pk4T + (size_t)B * K;
    float4* nz  = ke8 + 2 * K;
    float*  nl  = (float*)(nz + NB);

    // per-(b,k) oscillator constants: this block handles note b
    {
        float f0b = f0[b];
        float fr = f0b / 440.0f;
        float midi = 69.0f + 12.0f * (float)log2((double)fr);
        float mn = (midi - 21.0f) / 87.0f;
        float z = nofuse(slope * mn) + inter;
        z = fminf(fmaxf(z, -14.0f), -4.0f);
        float Binh = (float)exp((double)z);
        float pexp = (float)exp((double)pan_scale);
        int km1 = (K - 1) > 1 ? (K - 1) : 1;
        for (int k = tid; k < K; k += blockDim.x) {
            float kf = (float)(k + 1);
            float kk  = kf * kf;
            float bk2 = nofuse(Binh * kk);
            float arg = nofuse(1.0f + bk2);
            float s3  = (float)sqrt((double)arg);
            float r0  = nofuse(f0b * kf);
            float r1  = nofuse(r0 * s3);
            float dt  = nofuse(1.0f + harm_detune[k]);
            float fq  = nofuse(r1 * dt);
            float alive = (fq < 22050.0f) ? 1.0f : 0.0f;
            float amp = (float)exp((double)log_A0[k]) * vel[b] * alive;
            float a = (float)k / (float)km1;
            float pini = nofuse((a * 2.0f - 1.0f) * 0.1f);
            float pan = (float)tanh((double)nofuse(pini * pexp));
            float gl = (float)sqrt((double)(0.5f * (1.0f - pan)));
            float gr = (float)sqrt((double)(0.5f * (1.0f + pan)));
            float pf = nofuse(two_pi * fq);
            pk4T[(size_t)k * B + b] = make_float4(pf, amp * gl, amp * gr, 0.0f);
        }
    }

    if (b != 0) return;
    // shared (b-independent) tables: block 0 only
    for (int k = tid; k < K; k += blockDim.x) {
        float tau1 = (float)exp((double)log_tau1[k]);
        float tau2 = (float)exp((double)log_tau2[k]);
        float a1 = (float)(1.0 / (1.0 + exp(-(double)logit_a1[k])));
        float bhz = (float)exp((double)log_beat_hz[k]);
        float dep = (float)(1.0 / (1.0 + exp(-(double)logit_beat_depth[k])));
        ke8[2 * k]     = make_float4(LOG2E / tau1, LOG2E / tau2, a1, 1.0f - a1);
        ke8[2 * k + 1] = make_float4(bhz, 0.5f * dep, 0.0f, 0.0f);
    }
    for (int j = tid; j < NB; j += blockDim.x) {
        float m = -1e30f;
        for (int q = 0; q < NB; ++q) m = fmaxf(m, noise_band_gain[q]);
        float ssum = 0.0f;
        for (int q = 0; q < NB; ++q)
            ssum += (float)exp((double)(noise_band_gain[q] - m));
        double start = log(200.0), stop = log(20000.0);
        double step = (stop - start) / (double)(NB - 1);
        float lin = (j == NB - 1) ? (float)stop : (float)(start + (double)j * step);
        float nf = (float)exp((double)lin);
        float na = (nf < 22050.0f) ? 1.0f : 0.0f;
        float bg = ((float)exp((double)(noise_band_gain[j] - m)) / ssum) * na;
        nz[j] = make_float4(nofuse(two_pi * nf), bg, 0.0f, 0.0f);
    }
    for (int bb = tid; bb < B; bb += blockDim.x)
        nl[bb] = (float)exp((double)plog_noise_level[0]) * vel[bb];
    if (tid == 0) nl[B] = 1.0f / (float)exp((double)plog_tau_noise[0]);
}

// Fused synth. KC_CT > 0: compile-time chunk size -> full unroll.
// BT = notes per block (=B), table reads all scalar (s_load) via
// readfirstlane-derived SGPR indices.
template <int BT, int KC_CT, int NB_CT>
__global__ __launch_bounds__(512, 4) void pr_synth(
    const float4* __restrict__ pk4T, const float4* __restrict__ ke8,
    const float4* __restrict__ nz, const float* __restrict__ nlp,
    float* __restrict__ out, int B, int K, int NB, int N) {
    __shared__ float s_red[NCH][64][2 * BT + 1];   // stride 17: conflict-free

    const int tid  = threadIdx.x;
    const int lane = tid & 63;
    // SGPR wave index -> all table addresses provably uniform -> s_load
    const int g    = __builtin_amdgcn_readfirstlane(tid >> 6);

    const int n = blockIdx.x * 64 + lane;
    const float t = (float)n * (float)(1.0 / 44100.0);
    const float nt = -t;
    const int KC = (KC_CT > 0) ? KC_CT : ((K + NCH - 1) / NCH);
    const int k0 = g * KC;

    float accL[BT], accR[BT];
#pragma unroll
    for (int bi = 0; bi < BT; ++bi) { accL[bi] = 0.0f; accR[bi] = 0.0f; }

#pragma unroll
    for (int kk = 0; kk < ((KC_CT > 0) ? KC_CT : 1); ++kk) {
        // generic path: re-loop at runtime
        const int kEnd = (KC_CT > 0) ? (kk + 1) : (min(K, k0 + KC) - k0);
        for (int ki = kk; ki < kEnd; ++ki) {
            const int k = k0 + ki;
            float4 ka = ke8[2 * k];         // uniform -> s_load (batched by unroll)
            float4 kb = ke8[2 * k + 1];
            float e1 = exp2f(nt * ka.x);
            float e2 = exp2f(nt * ka.y);
            float env = ka.z * e1 + ka.w * e2;
            float beat = fmaf(kb.y, __builtin_amdgcn_cosf(kb.x * t) - 1.0f, 1.0f);
            float eb = env * beat;
            const float4* pk = pk4T + (size_t)k * BT;
#pragma unroll
            for (int bi = 0; bi < BT; ++bi) {
                float4 p = pk[bi];          // uniform, 128B contiguous -> s_load
                float ph = p.x * t;
                float q = rintf(ph * INV2PI);
                float r = fmaf(q, -C2PI_HI, ph);
                r = fmaf(q, -C2PI_LO, r);
                float sv = __sinf(r);
                float pp = eb * sv;
                accL[bi] = fmaf(p.y, pp, accL[bi]);
                accR[bi] = fmaf(p.z, pp, accR[bi]);
            }
        }
    }

#pragma unroll
    for (int bi = 0; bi < BT; ++bi) {
        s_red[g][lane][2 * bi + 0] = accL[bi];
        s_red[g][lane][2 * bi + 1] = accR[bi];
    }

    // attack noise: independent of s_red -> compute BEFORE the barrier so
    // it overlaps other waves' LDS writes / barrier latency.
    float ns = 0.0f;
    const int NBL = (NB_CT > 0) ? NB_CT : NB;
#pragma unroll
    for (int j = 0; j < ((NB_CT > 0) ? NB_CT : NBMAX); ++j) {
        if (NB_CT == 0 && j >= NBL) break;
        float4 zj = nz[j];              // uniform -> s_load
        ns = fmaf(zj.y, sin_cw(zj.x * t), ns);
    }
    float itn = nlp[B];                 // scalar
    float nsv = ns * __expf(nt * itn);

    __syncthreads();

    const int JT = (2 * BT) / NCH;      // outputs per wave (2)
    if (n < N) {
#pragma unroll
        for (int jj = 0; jj < JT; ++jj) {
            int j = g * JT + jj;
            int b = j >> 1;
            if (b >= B) continue;
            float s = 0.0f;
#pragma unroll
            for (int c = 0; c < NCH; ++c) s += s_red[c][lane][j];
            float nois = nlp[b] * nsv;
            out[(size_t)j * N + n] = s + nois;
        }
    }
}

extern "C" void kernel_launch(void* const* d_in, const int* in_sizes, int n_in,
                              void* d_out, int out_size, void* d_ws, size_t ws_size,
                              hipStream_t stream) {
    const float* f0    = (const float*)d_in[0];
    const float* vel   = (const float*)d_in[1];
    const float* slope = (const float*)d_in[2];
    const float* inter = (const float*)d_in[3];
    const float* lt1   = (const float*)d_in[4];
    const float* lt2   = (const float*)d_in[5];
    const float* la1   = (const float*)d_in[6];
    const float* lbh   = (const float*)d_in[7];
    const float* lbd   = (const float*)d_in[8];
    const float* lA0   = (const float*)d_in[9];
    const float* hdet  = (const float*)d_in[10];
    const float* nbg   = (const float*)d_in[11];
    const float* ltn   = (const float*)d_in[12];
    const float* lnl   = (const float*)d_in[13];
    const float* pans  = (const float*)d_in[14];

    const int B  = in_sizes[0];
    const int K  = in_sizes[4];
    const int NB = in_sizes[11];
    const int N  = out_size / (2 * B);

    float* ws = (float*)d_ws;

    hipLaunchKernelGGL(pr_precomp, dim3(B), dim3(128), 0, stream,
                       f0, vel, slope, inter, lt1, lt2, la1, lbh, lbd, lA0,
                       hdet, nbg, ltn, lnl, pans, ws, B, K, NB);

    const float4* pk4T = (const float4*)ws;
    const float4* ke8 = pk4T + (size_t)B * K;
    const float4* nz  = ke8 + 2 * K;
    const float*  nlp = (const float*)(nz + NB);

    dim3 grid((N + 63) / 64);
    if (B == 8 && K == 80 && NB == 16) {
        // specialized: KC = 80/8 = 10, fully unrolled k-loop
        hipLaunchKernelGGL((pr_synth<8, 10, 16>), grid, dim3(512), 0, stream,
                           pk4T, ke8, nz, nlp, (float*)d_out, B, K, NB, N);
    } else {
        hipLaunchKernelGGL((pr_synth<8, 0, 0>), grid, dim3(512), 0, stream,
                           pk4T, ke8, nz, nlp, (float*)d_out, B, K, NB, N);
    }
}

// Round 10
// 106.039 us; speedup vs baseline: 1.0490x; 1.0490x over previous
//
#include <hip/hip_runtime.h>
#include <math.h>

// ---------------------------------------------------------------------------
// PhysicsResonatorBank: B=8 notes, K=80 partials, NB=16 noise bands,
// N = n_frames*256 samples. out[b][c][n], c in {L,R}.
//
// Round-10 structure (512 thr = 8 waves, wave g owns k-chunk g, scalar
// tables via readfirstlane-SGPR indices, full k-unroll), PLUS:
//  - SEPARABLE amp: cl[b][k] = (A0[k]*gl[k]) * vel[b]. Per-k u[k],w[k]
//    packed in ke8[2k+1].zw; vel applied once in the epilogue; alive
//    mask folded into pf=0 (sin(0)=0 -> exact zero contribution).
//    pf table is now 32 B/k (was 128 B) -> lighter SMEM + SGPR pressure.
//  - noise computed by wave 0 ONLY, broadcast via LDS s_ns[64]
//    (was computed redundantly by all 8 waves).
//  - bare v_sin/v_cos/v_exp builtins (revolutions; proven in r6-r9).
// sin(phase) matches the reference's exact f32 phase fl(fl(2pi*f)*t) via
// 2-term Cody-Waite + v_sin on the reduced argument.
// ---------------------------------------------------------------------------

#define NBMAX 32
#define NCH 8

#define C2PI_HI 6.28318548202514648f     // fl32(2*pi)
#define C2PI_LO -1.7484556e-7f           // fl32(2*pi - C2PI_HI)
#define INV2PI  0.15915494309189535f
#define LOG2E   1.44269504088896340736f

__device__ __forceinline__ float nofuse(float x) {
    asm volatile("" : "+v"(x));
    return x;
}

__device__ __forceinline__ float sin_cw(float ph) {
    float q = rintf(ph * INV2PI);
    float r = fmaf(q, -C2PI_HI, ph);
    r = fmaf(q, -C2PI_LO, r);
    return __builtin_amdgcn_sinf(r * INV2PI);   // v_sin, revolutions
}

// ws layout (floats):
//  float  pfT[align4(K*B)] : [k][b] = 2pi*f (0 if dead partial)
//  float4 ke8[2*K]  : [2k]   = {log2e/tau1, log2e/tau2, a1, 1-a1}
//                     [2k+1] = {beat_hz (rev/s), 0.5*depth, u[k], w[k]}
//                     u[k]=exp(log_A0[k])*gl[k], w[k]=exp(log_A0[k])*gr[k]
//  float4 nz [NB]   : {2pi*nf, band_gain, 0, 0}
//  float  nl [B]    : exp(log_noise_level)*vel ; nl[B] = 1/tau_noise
//  float  vl [B]    : vel

__global__ void pr_precomp(const float* __restrict__ f0,
                           const float* __restrict__ vel,
                           const float* __restrict__ pslope,
                           const float* __restrict__ pinter,
                           const float* __restrict__ log_tau1,
                           const float* __restrict__ log_tau2,
                           const float* __restrict__ logit_a1,
                           const float* __restrict__ log_beat_hz,
                           const float* __restrict__ logit_beat_depth,
                           const float* __restrict__ log_A0,
                           const float* __restrict__ harm_detune,
                           const float* __restrict__ noise_band_gain,
                           const float* __restrict__ plog_tau_noise,
                           const float* __restrict__ plog_noise_level,
                           const float* __restrict__ ppan_scale,
                           float* __restrict__ ws, int B, int K, int NB) {
    const int tid = threadIdx.x;
    const int b = blockIdx.x;           // grid = B blocks
    const float two_pi = C2PI_HI;
    const float slope = pslope[0], inter = pinter[0], pan_scale = ppan_scale[0];

    const size_t pfA = ((size_t)K * B + 3) & ~(size_t)3;
    float*  pfT = ws;
    float4* ke8 = (float4*)(ws + pfA);
    float4* nz  = ke8 + 2 * K;
    float*  nl  = (float*)(nz + NB);
    float*  vl  = nl + B + 1;

    // per-(b,k) phase-rate (this block handles note b); 0 for dead partials
    {
        float f0b = f0[b];
        float fr = f0b / 440.0f;
        float midi = 69.0f + 12.0f * (float)log2((double)fr);
        float mn = (midi - 21.0f) / 87.0f;
        float z = nofuse(slope * mn) + inter;
        z = fminf(fmaxf(z, -14.0f), -4.0f);
        float Binh = (float)exp((double)z);
        for (int k = tid; k < K; k += blockDim.x) {
            float kf = (float)(k + 1);
            float kk  = kf * kf;
            float bk2 = nofuse(Binh * kk);
            float arg = nofuse(1.0f + bk2);
            float s3  = (float)sqrt((double)arg);
            float r0  = nofuse(f0b * kf);
            float r1  = nofuse(r0 * s3);
            float dt  = nofuse(1.0f + harm_detune[k]);
            float fq  = nofuse(r1 * dt);
            float pf = nofuse(two_pi * fq);
            pfT[(size_t)k * B + b] = (fq < 22050.0f) ? pf : 0.0f;
        }
    }

    if (b != 0) return;
    // shared (b-independent) tables: block 0 only
    {
        float pexp = (float)exp((double)pan_scale);
        int km1 = (K - 1) > 1 ? (K - 1) : 1;
        for (int k = tid; k < K; k += blockDim.x) {
            float tau1 = (float)exp((double)log_tau1[k]);
            float tau2 = (float)exp((double)log_tau2[k]);
            float a1 = (float)(1.0 / (1.0 + exp(-(double)logit_a1[k])));
            float bhz = (float)exp((double)log_beat_hz[k]);
            float dep = (float)(1.0 / (1.0 + exp(-(double)logit_beat_depth[k])));
            float a = (float)k / (float)km1;
            float pini = nofuse((a * 2.0f - 1.0f) * 0.1f);
            float pan = (float)tanh((double)nofuse(pini * pexp));
            float gl = (float)sqrt((double)(0.5f * (1.0f - pan)));
            float gr = (float)sqrt((double)(0.5f * (1.0f + pan)));
            float A0 = (float)exp((double)log_A0[k]);
            ke8[2 * k]     = make_float4(LOG2E / tau1, LOG2E / tau2, a1, 1.0f - a1);
            ke8[2 * k + 1] = make_float4(bhz, 0.5f * dep, A0 * gl, A0 * gr);
        }
    }
    for (int j = tid; j < NB; j += blockDim.x) {
        float m = -1e30f;
        for (int q = 0; q < NB; ++q) m = fmaxf(m, noise_band_gain[q]);
        float ssum = 0.0f;
        for (int q = 0; q < NB; ++q)
            ssum += (float)exp((double)(noise_band_gain[q] - m));
        double start = log(200.0), stop = log(20000.0);
        double step = (stop - start) / (double)(NB - 1);
        float lin = (j == NB - 1) ? (float)stop : (float)(start + (double)j * step);
        float nf = (float)exp((double)lin);
        float na = (nf < 22050.0f) ? 1.0f : 0.0f;
        float bg = ((float)exp((double)(noise_band_gain[j] - m)) / ssum) * na;
        nz[j] = make_float4(nofuse(two_pi * nf), bg, 0.0f, 0.0f);
    }
    for (int bb = tid; bb < B; bb += blockDim.x) {
        nl[bb] = (float)exp((double)plog_noise_level[0]) * vel[bb];
        vl[bb] = vel[bb];
    }
    if (tid == 0) nl[B] = 1.0f / (float)exp((double)plog_tau_noise[0]);
}

// Fused synth. KC_CT > 0: compile-time chunk size -> full unroll.
// Tables all scalar (s_load) via readfirstlane-derived SGPR indices.
template <int BT, int KC_CT, int NB_CT>
__global__ __launch_bounds__(512, 8) void pr_synth(
    const float* __restrict__ pfT, const float4* __restrict__ ke8,
    const float4* __restrict__ nz, const float* __restrict__ nlp,
    float* __restrict__ out, int B, int K, int NB, int N) {
    __shared__ float s_red[NCH][64][2 * BT + 1];   // stride 17: conflict-free
    __shared__ float s_ns[64];

    const int tid  = threadIdx.x;
    const int lane = tid & 63;
    // SGPR wave index -> all table addresses provably uniform -> s_load
    const int g    = __builtin_amdgcn_readfirstlane(tid >> 6);

    const int n = blockIdx.x * 64 + lane;
    const float t = (float)n * (float)(1.0 / 44100.0);
    const float nt = -t;
    const int KC = (KC_CT > 0) ? KC_CT : ((K + NCH - 1) / NCH);
    const int k0 = g * KC;

    float accL[BT], accR[BT];
#pragma unroll
    for (int bi = 0; bi < BT; ++bi) { accL[bi] = 0.0f; accR[bi] = 0.0f; }

#pragma unroll
    for (int kk = 0; kk < ((KC_CT > 0) ? KC_CT : 1); ++kk) {
        // generic path: re-loop at runtime
        const int kEnd = (KC_CT > 0) ? (kk + 1) : (min(K, k0 + KC) - k0);
        for (int ki = kk; ki < kEnd; ++ki) {
            const int k = k0 + ki;
            float4 ka = ke8[2 * k];         // uniform -> s_load
            float4 kb = ke8[2 * k + 1];
            float e1 = exp2f(nt * ka.x);
            float e2 = exp2f(nt * ka.y);
            float env = ka.z * e1 + ka.w * e2;
            float beat = fmaf(kb.y, __builtin_amdgcn_cosf(kb.x * t) - 1.0f, 1.0f);
            float eb = env * beat;
            float ueb = kb.z * eb;
            float web = kb.w * eb;
            const float* pf = pfT + (size_t)k * B;
#pragma unroll
            for (int bi = 0; bi < BT; ++bi) {
                float p = pf[bi];           // uniform, contiguous -> s_load
                float ph = p * t;
                float q = rintf(ph * INV2PI);
                float r = fmaf(q, -C2PI_HI, ph);
                r = fmaf(q, -C2PI_LO, r);
                float sv = __builtin_amdgcn_sinf(r * INV2PI);
                accL[bi] = fmaf(ueb, sv, accL[bi]);
                accR[bi] = fmaf(web, sv, accR[bi]);
            }
        }
    }

#pragma unroll
    for (int bi = 0; bi < BT; ++bi) {
        s_red[g][lane][2 * bi + 0] = accL[bi];
        s_red[g][lane][2 * bi + 1] = accR[bi];
    }

    // attack noise: ONE wave computes it for the block's 64 samples
    // (identical across waves), broadcast through LDS.
    if (g == 0) {
        float ns = 0.0f;
        const int NBL = (NB_CT > 0) ? NB_CT : NB;
#pragma unroll
        for (int j = 0; j < ((NB_CT > 0) ? NB_CT : NBMAX); ++j) {
            if (NB_CT == 0 && j >= NBL) break;
            float4 zj = nz[j];              // uniform -> s_load
            ns = fmaf(zj.y, sin_cw(zj.x * t), ns);
        }
        float itn = nlp[B];                 // scalar
        s_ns[lane] = ns * exp2f(nt * (itn * LOG2E));
    }

    __syncthreads();

    const float* vl = nlp + B + 1;
    const float nsv = s_ns[lane];
    const int JT = (2 * BT) / NCH;          // outputs per wave
    if (n < N) {
#pragma unroll
        for (int jj = 0; jj < JT; ++jj) {
            int j = g * JT + jj;
            int b = j >> 1;
            if (b >= B) continue;
            float s = 0.0f;
#pragma unroll
            for (int c = 0; c < NCH; ++c) s += s_red[c][lane][j];
            out[(size_t)j * N + n] = vl[b] * s + nlp[b] * nsv;
        }
    }
}

extern "C" void kernel_launch(void* const* d_in, const int* in_sizes, int n_in,
                              void* d_out, int out_size, void* d_ws, size_t ws_size,
                              hipStream_t stream) {
    const float* f0    = (const float*)d_in[0];
    const float* vel   = (const float*)d_in[1];
    const float* slope = (const float*)d_in[2];
    const float* inter = (const float*)d_in[3];
    const float* lt1   = (const float*)d_in[4];
    const float* lt2   = (const float*)d_in[5];
    const float* la1   = (const float*)d_in[6];
    const float* lbh   = (const float*)d_in[7];
    const float* lbd   = (const float*)d_in[8];
    const float* lA0   = (const float*)d_in[9];
    const float* hdet  = (const float*)d_in[10];
    const float* nbg   = (const float*)d_in[11];
    const float* ltn   = (const float*)d_in[12];
    const float* lnl   = (const float*)d_in[13];
    const float* pans  = (const float*)d_in[14];

    const int B  = in_sizes[0];
    const int K  = in_sizes[4];
    const int NB = in_sizes[11];
    const int N  = out_size / (2 * B);

    float* ws = (float*)d_ws;

    hipLaunchKernelGGL(pr_precomp, dim3(B), dim3(128), 0, stream,
                       f0, vel, slope, inter, lt1, lt2, la1, lbh, lbd, lA0,
                       hdet, nbg, ltn, lnl, pans, ws, B, K, NB);

    const size_t pfA = ((size_t)K * B + 3) & ~(size_t)3;
    const float*  pfT = ws;
    const float4* ke8 = (const float4*)(ws + pfA);
    const float4* nz  = ke8 + 2 * K;
    const float*  nlp = (const float*)(nz + NB);

    dim3 grid((N + 63) / 64);
    if (B == 8 && K == 80 && NB == 16) {
        // specialized: KC = 80/8 = 10, fully unrolled k-loop
        hipLaunchKernelGGL((pr_synth<8, 10, 16>), grid, dim3(512), 0, stream,
                           pfT, ke8, nz, nlp, (float*)d_out, B, K, NB, N);
    } else {
        hipLaunchKernelGGL((pr_synth<8, 0, 0>), grid, dim3(512), 0, stream,
                           pfT, ke8, nz, nlp, (float*)d_out, B, K, NB, N);
    }
}

// Round 11
// 104.041 us; speedup vs baseline: 1.0691x; 1.0192x over previous
//
#include <hip/hip_runtime.h>
#include <math.h>

// ---------------------------------------------------------------------------
// PhysicsResonatorBank: B=8 notes, K=80 partials, NB=16 noise bands,
// N = n_frames*256 samples. out[b][c][n], c in {L,R}.
//
// Round-11 (consolidation on round-10 best):
//  - Revolution-space Cody-Waite: q=rint(ph*I2PI); rv=fma(ph,I2PI,-q);
//    rv=fma(ph,I2PI_LO,rv); v_sin(rv). One VALU op fewer per (b,k) chain
//    than radian-space CW + final mul (residual error ~6e-7 rad, harmless).
//  - Attack noise split across all 8 waves (bands g, g+8 per wave) via a
//    2 KB LDS partial buffer -- removes the ~300-cycle wave-0 serial noise
//    tail that all waves waited out at the barrier (round-10 form).
//  - 1/tau_noise pre-scaled by log2e in precomp.
// Structure otherwise identical to round 10: 512 thr = 8 waves, wave g
// owns k-chunk g (10 partials) for 64 samples x all 8 notes; separable
// amp (vel in epilogue, alive-mask folded into pf=0); all tables read via
// scalar loads off readfirstlane-SGPR indices; full k-unroll (K=80
// specialization); LDS only for the padded cross-wave reduction buffer.
// sin(phase) matches the reference's exact f32 phase fl(fl(2pi*f)*t).
// ---------------------------------------------------------------------------

#define NBMAX 32
#define NCH 8

#define C2PI_HI 6.28318548202514648f     // fl32(2*pi)
#define C2PI_LO -1.7484556e-7f           // fl32(2*pi - C2PI_HI)
#define INV2PI  0.15915494309189535f     // rounds to 0x3E22F983
#define I2PI_LO 6.4206379e-9f            // 1/(2pi) - fl32(1/(2pi))
#define LOG2E   1.44269504088896340736f

__device__ __forceinline__ float nofuse(float x) {
    asm volatile("" : "+v"(x));
    return x;
}

// sin of an f32 phase (radians) via revolution-space 2-term Cody-Waite:
// q integer revolutions; rv = frac revolutions, accurate to ~1e-7 rev.
__device__ __forceinline__ float sin_cw(float ph) {
    float q = rintf(ph * INV2PI);
    float rv = fmaf(ph, INV2PI, -q);
    rv = fmaf(ph, I2PI_LO, rv);
    return __builtin_amdgcn_sinf(rv);   // v_sin, revolutions
}

// ws layout (floats):
//  float  pfT[align4(K*B)] : [k][b] = 2pi*f (0 if dead partial)
//  float4 ke8[2*K]  : [2k]   = {log2e/tau1, log2e/tau2, a1, 1-a1}
//                     [2k+1] = {beat_hz (rev/s), 0.5*depth, u[k], w[k]}
//                     u[k]=exp(log_A0[k])*gl[k], w[k]=exp(log_A0[k])*gr[k]
//  float4 nz [NB]   : {2pi*nf, band_gain, 0, 0}
//  float  nl [B]    : exp(log_noise_level)*vel ; nl[B] = log2e/tau_noise
//  float  vl [B]    : vel

__global__ void pr_precomp(const float* __restrict__ f0,
                           const float* __restrict__ vel,
                           const float* __restrict__ pslope,
                           const float* __restrict__ pinter,
                           const float* __restrict__ log_tau1,
                           const float* __restrict__ log_tau2,
                           const float* __restrict__ logit_a1,
                           const float* __restrict__ log_beat_hz,
                           const float* __restrict__ logit_beat_depth,
                           const float* __restrict__ log_A0,
                           const float* __restrict__ harm_detune,
                           const float* __restrict__ noise_band_gain,
                           const float* __restrict__ plog_tau_noise,
                           const float* __restrict__ plog_noise_level,
                           const float* __restrict__ ppan_scale,
                           float* __restrict__ ws, int B, int K, int NB) {
    const int tid = threadIdx.x;
    const int b = blockIdx.x;           // grid = B blocks
    const float two_pi = C2PI_HI;
    const float slope = pslope[0], inter = pinter[0], pan_scale = ppan_scale[0];

    const size_t pfA = ((size_t)K * B + 3) & ~(size_t)3;
    float*  pfT = ws;
    float4* ke8 = (float4*)(ws + pfA);
    float4* nz  = ke8 + 2 * K;
    float*  nl  = (float*)(nz + NB);
    float*  vl  = nl + B + 1;

    // per-(b,k) phase-rate (this block handles note b); 0 for dead partials
    {
        float f0b = f0[b];
        float fr = f0b / 440.0f;
        float midi = 69.0f + 12.0f * (float)log2((double)fr);
        float mn = (midi - 21.0f) / 87.0f;
        float z = nofuse(slope * mn) + inter;
        z = fminf(fmaxf(z, -14.0f), -4.0f);
        float Binh = (float)exp((double)z);
        for (int k = tid; k < K; k += blockDim.x) {
            float kf = (float)(k + 1);
            float kk  = kf * kf;
            float bk2 = nofuse(Binh * kk);
            float arg = nofuse(1.0f + bk2);
            float s3  = (float)sqrt((double)arg);
            float r0  = nofuse(f0b * kf);
            float r1  = nofuse(r0 * s3);
            float dt  = nofuse(1.0f + harm_detune[k]);
            float fq  = nofuse(r1 * dt);
            float pf = nofuse(two_pi * fq);
            pfT[(size_t)k * B + b] = (fq < 22050.0f) ? pf : 0.0f;
        }
    }

    if (b != 0) return;
    // shared (b-independent) tables: block 0 only
    {
        float pexp = (float)exp((double)pan_scale);
        int km1 = (K - 1) > 1 ? (K - 1) : 1;
        for (int k = tid; k < K; k += blockDim.x) {
            float tau1 = (float)exp((double)log_tau1[k]);
            float tau2 = (float)exp((double)log_tau2[k]);
            float a1 = (float)(1.0 / (1.0 + exp(-(double)logit_a1[k])));
            float bhz = (float)exp((double)log_beat_hz[k]);
            float dep = (float)(1.0 / (1.0 + exp(-(double)logit_beat_depth[k])));
            float a = (float)k / (float)km1;
            float pini = nofuse((a * 2.0f - 1.0f) * 0.1f);
            float pan = (float)tanh((double)nofuse(pini * pexp));
            float gl = (float)sqrt((double)(0.5f * (1.0f - pan)));
            float gr = (float)sqrt((double)(0.5f * (1.0f + pan)));
            float A0 = (float)exp((double)log_A0[k]);
            ke8[2 * k]     = make_float4(LOG2E / tau1, LOG2E / tau2, a1, 1.0f - a1);
            ke8[2 * k + 1] = make_float4(bhz, 0.5f * dep, A0 * gl, A0 * gr);
        }
    }
    for (int j = tid; j < NB; j += blockDim.x) {
        float m = -1e30f;
        for (int q = 0; q < NB; ++q) m = fmaxf(m, noise_band_gain[q]);
        float ssum = 0.0f;
        for (int q = 0; q < NB; ++q)
            ssum += (float)exp((double)(noise_band_gain[q] - m));
        double start = log(200.0), stop = log(20000.0);
        double step = (stop - start) / (double)(NB - 1);
        float lin = (j == NB - 1) ? (float)stop : (float)(start + (double)j * step);
        float nf = (float)exp((double)lin);
        float na = (nf < 22050.0f) ? 1.0f : 0.0f;
        float bg = ((float)exp((double)(noise_band_gain[j] - m)) / ssum) * na;
        nz[j] = make_float4(nofuse(two_pi * nf), bg, 0.0f, 0.0f);
    }
    for (int bb = tid; bb < B; bb += blockDim.x) {
        nl[bb] = (float)exp((double)plog_noise_level[0]) * vel[bb];
        vl[bb] = vel[bb];
    }
    if (tid == 0) nl[B] = LOG2E / (float)exp((double)plog_tau_noise[0]);
}

// Fused synth. KC_CT > 0: compile-time chunk size -> full unroll.
// Tables all scalar (s_load) via readfirstlane-derived SGPR indices.
template <int BT, int KC_CT, int NB_CT>
__global__ __launch_bounds__(512, 8) void pr_synth(
    const float* __restrict__ pfT, const float4* __restrict__ ke8,
    const float4* __restrict__ nz, const float* __restrict__ nlp,
    float* __restrict__ out, int B, int K, int NB, int N) {
    __shared__ float s_red[NCH][64][2 * BT + 1];   // stride 17: conflict-free
    __shared__ float s_nsp[NCH][64];               // per-wave noise partials

    const int tid  = threadIdx.x;
    const int lane = tid & 63;
    // SGPR wave index -> all table addresses provably uniform -> s_load
    const int g    = __builtin_amdgcn_readfirstlane(tid >> 6);

    const int n = blockIdx.x * 64 + lane;
    const float t = (float)n * (float)(1.0 / 44100.0);
    const float nt = -t;
    const int KC = (KC_CT > 0) ? KC_CT : ((K + NCH - 1) / NCH);
    const int k0 = g * KC;

    float accL[BT], accR[BT];
#pragma unroll
    for (int bi = 0; bi < BT; ++bi) { accL[bi] = 0.0f; accR[bi] = 0.0f; }

#pragma unroll
    for (int kk = 0; kk < ((KC_CT > 0) ? KC_CT : 1); ++kk) {
        // generic path: re-loop at runtime
        const int kEnd = (KC_CT > 0) ? (kk + 1) : (min(K, k0 + KC) - k0);
        for (int ki = kk; ki < kEnd; ++ki) {
            const int k = k0 + ki;
            float4 ka = ke8[2 * k];         // uniform -> s_load
            float4 kb = ke8[2 * k + 1];
            float e1 = exp2f(nt * ka.x);
            float e2 = exp2f(nt * ka.y);
            float env = ka.z * e1 + ka.w * e2;
            float beat = fmaf(kb.y, __builtin_amdgcn_cosf(kb.x * t) - 1.0f, 1.0f);
            float eb = env * beat;
            float ueb = kb.z * eb;
            float web = kb.w * eb;
            const float* pf = pfT + (size_t)k * B;
#pragma unroll
            for (int bi = 0; bi < BT; ++bi) {
                float p = pf[bi];           // uniform, contiguous -> s_load
                float ph = p * t;
                float q = rintf(ph * INV2PI);
                float rv = fmaf(ph, INV2PI, -q);
                rv = fmaf(ph, I2PI_LO, rv);
                float sv = __builtin_amdgcn_sinf(rv);
                accL[bi] = fmaf(ueb, sv, accL[bi]);
                accR[bi] = fmaf(web, sv, accR[bi]);
            }
        }
    }

#pragma unroll
    for (int bi = 0; bi < BT; ++bi) {
        s_red[g][lane][2 * bi + 0] = accL[bi];
        s_red[g][lane][2 * bi + 1] = accR[bi];
    }

    // attack noise: split across waves (wave g -> bands g, g+NCH, ...),
    // partials exchanged via LDS alongside s_red.
    {
        float ns = 0.0f;
        const int NBL = (NB_CT > 0) ? NB_CT : NB;
#pragma unroll
        for (int jj = 0; jj < ((NB_CT > 0) ? (NB_CT + NCH - 1) / NCH
                                           : NBMAX / NCH); ++jj) {
            int j = g + jj * NCH;
            if (NB_CT == 0 && j >= NBL) break;
            if (NB_CT > 0 && j >= NB_CT) break;
            float4 zj = nz[j];              // uniform -> s_load
            ns = fmaf(zj.y, sin_cw(zj.x * t), ns);
        }
        s_nsp[g][lane] = ns;
    }

    __syncthreads();

    const float* vl = nlp + B + 1;
    float nsum = 0.0f;
#pragma unroll
    for (int c = 0; c < NCH; ++c) nsum += s_nsp[c][lane];
    const float nsv = nsum * exp2f(nt * nlp[B]);   // nlp[B] = log2e/tau_n

    const int JT = (2 * BT) / NCH;          // outputs per wave
    if (n < N) {
#pragma unroll
        for (int jj = 0; jj < JT; ++jj) {
            int j = g * JT + jj;
            int b = j >> 1;
            if (b >= B) continue;
            float s = 0.0f;
#pragma unroll
            for (int c = 0; c < NCH; ++c) s += s_red[c][lane][j];
            out[(size_t)j * N + n] = vl[b] * s + nlp[b] * nsv;
        }
    }
}

extern "C" void kernel_launch(void* const* d_in, const int* in_sizes, int n_in,
                              void* d_out, int out_size, void* d_ws, size_t ws_size,
                              hipStream_t stream) {
    const float* f0    = (const float*)d_in[0];
    const float* vel   = (const float*)d_in[1];
    const float* slope = (const float*)d_in[2];
    const float* inter = (const float*)d_in[3];
    const float* lt1   = (const float*)d_in[4];
    const float* lt2   = (const float*)d_in[5];
    const float* la1   = (const float*)d_in[6];
    const float* lbh   = (const float*)d_in[7];
    const float* lbd   = (const float*)d_in[8];
    const float* lA0   = (const float*)d_in[9];
    const float* hdet  = (const float*)d_in[10];
    const float* nbg   = (const float*)d_in[11];
    const float* ltn   = (const float*)d_in[12];
    const float* lnl   = (const float*)d_in[13];
    const float* pans  = (const float*)d_in[14];

    const int B  = in_sizes[0];
    const int K  = in_sizes[4];
    const int NB = in_sizes[11];
    const int N  = out_size / (2 * B);

    float* ws = (float*)d_ws;

    hipLaunchKernelGGL(pr_precomp, dim3(B), dim3(128), 0, stream,
                       f0, vel, slope, inter, lt1, lt2, la1, lbh, lbd, lA0,
                       hdet, nbg, ltn, lnl, pans, ws, B, K, NB);

    const size_t pfA = ((size_t)K * B + 3) & ~(size_t)3;
    const float*  pfT = ws;
    const float4* ke8 = (const float4*)(ws + pfA);
    const float4* nz  = ke8 + 2 * K;
    const float*  nlp = (const float*)(nz + NB);

    dim3 grid((N + 63) / 64);
    if (B == 8 && K == 80 && NB == 16) {
        // specialized: KC = 80/8 = 10, fully unrolled k-loop
        hipLaunchKernelGGL((pr_synth<8, 10, 16>), grid, dim3(512), 0, stream,
                           pfT, ke8, nz, nlp, (float*)d_out, B, K, NB, N);
    } else {
        hipLaunchKernelGGL((pr_synth<8, 0, 0>), grid, dim3(512), 0, stream,
                           pfT, ke8, nz, nlp, (float*)d_out, B, K, NB, N);
    }
}